// Round 1
// baseline (414.807 us; speedup 1.0000x reference)
//
#include <hip/hip_runtime.h>
#include <math.h>

#define B_ 4
#define F_ 16
#define N_ 1024
#define V_ 4

// ---------------- workspace layout ----------------
// d_ws is re-poisoned to 0xAA before every timed launch, so init_ws must run
// first on every kernel_launch call.
//   double sums[3];      // [0]=rec SE sum, [1]=ident view_loss sum, [2]=att bce sum
//   unsigned mm[7];      // [0]=valid count, [1..3]=ordered min(gt xyz), [4..6]=ordered max
// (mm lives at byte offset 24)

__device__ __forceinline__ unsigned ordEncode(float f) {
    unsigned u = __float_as_uint(f);
    return (u & 0x80000000u) ? ~u : (u | 0x80000000u);
}
__device__ __forceinline__ float ordDecode(unsigned o) {
    unsigned u = (o & 0x80000000u) ? (o & 0x7FFFFFFFu) : ~o;
    return __uint_as_float(u);
}

__global__ void init_ws(double* sums, unsigned* mm) {
    int t = threadIdx.x;
    if (t < 3) sums[t] = 0.0;
    if (t < 7) mm[t] = (t >= 1 && t <= 3) ? 0xFFFFFFFFu : 0u;  // min slots -> +inf, max/count -> 0
}

// ---------------- reconstruction loss reductions ----------------
__global__ __launch_bounds__(256) void rec_kernel(const float* __restrict__ pred,
                                                  const float* __restrict__ gt,
                                                  const int* __restrict__ vis,
                                                  double* sums, unsigned* mm) {
    int p = blockIdx.x * 256 + threadIdx.x;   // exactly B*F*N = 65536 threads
    bool m = vis[p] > 0;
    float gx = gt[3 * p], gy = gt[3 * p + 1], gz = gt[3 * p + 2];
    float px = pred[3 * p], py = pred[3 * p + 1], pz = pred[3 * p + 2];
    float se = 0.f;
    if (m) {
        float dx = px - gx, dy = py - gy, dz = pz - gz;
        se = dx * dx + dy * dy + dz * dz;
    }
    float mn0 = m ? gx : 1e30f, mn1 = m ? gy : 1e30f, mn2 = m ? gz : 1e30f;
    float mx0 = m ? gx : -1e30f, mx1 = m ? gy : -1e30f, mx2 = m ? gz : -1e30f;
    float c = m ? 1.f : 0.f;
    #pragma unroll
    for (int off = 32; off; off >>= 1) {
        se += __shfl_down(se, off);
        c  += __shfl_down(c, off);
        mn0 = fminf(mn0, __shfl_down(mn0, off));
        mn1 = fminf(mn1, __shfl_down(mn1, off));
        mn2 = fminf(mn2, __shfl_down(mn2, off));
        mx0 = fmaxf(mx0, __shfl_down(mx0, off));
        mx1 = fmaxf(mx1, __shfl_down(mx1, off));
        mx2 = fmaxf(mx2, __shfl_down(mx2, off));
    }
    __shared__ float sh[4][8];
    int wave = threadIdx.x >> 6, lane = threadIdx.x & 63;
    if (lane == 0) {
        sh[wave][0] = se; sh[wave][1] = c;
        sh[wave][2] = mn0; sh[wave][3] = mn1; sh[wave][4] = mn2;
        sh[wave][5] = mx0; sh[wave][6] = mx1; sh[wave][7] = mx2;
    }
    __syncthreads();
    if (threadIdx.x == 0) {
        se = sh[0][0]; c = sh[0][1];
        mn0 = sh[0][2]; mn1 = sh[0][3]; mn2 = sh[0][4];
        mx0 = sh[0][5]; mx1 = sh[0][6]; mx2 = sh[0][7];
        for (int w = 1; w < 4; w++) {
            se += sh[w][0]; c += sh[w][1];
            mn0 = fminf(mn0, sh[w][2]); mn1 = fminf(mn1, sh[w][3]); mn2 = fminf(mn2, sh[w][4]);
            mx0 = fmaxf(mx0, sh[w][5]); mx1 = fmaxf(mx1, sh[w][6]); mx2 = fmaxf(mx2, sh[w][7]);
        }
        atomicAdd(&sums[0], (double)se);
        atomicAdd(&mm[0], (unsigned)(c + 0.5f));
        atomicMin(&mm[1], ordEncode(mn0));
        atomicMin(&mm[2], ordEncode(mn1));
        atomicMin(&mm[3], ordEncode(mn2));
        atomicMax(&mm[4], ordEncode(mx0));
        atomicMax(&mm[5], ordEncode(mx1));
        atomicMax(&mm[6], ordEncode(mx2));
    }
}

// ---------------- identity (reprojection) loss ----------------
// one block per (v,b,f); 256 threads over N=1024 points
__global__ __launch_bounds__(256) void ident_kernel(const float* __restrict__ pred,
                                                    const float* __restrict__ proj,
                                                    const float* __restrict__ tracks,
                                                    double* sums) {
    int idx = blockIdx.x;                    // 0..255
    int v = idx / (B_ * F_);
    int b = (idx / F_) % B_;
    int f = idx % F_;
    const float* P = proj + ((size_t)(v * B_ + b)) * 12;
    const float* T = tracks + ((size_t)((v * B_ + b) * F_ + f)) * N_ * 2;
    const float* Q = pred + ((size_t)(b * F_ + f)) * N_ * 3;

    // pass 1: track min/max over valid points
    float mnx = 1e30f, mny = 1e30f, mxx = -1e30f, mxy = -1e30f;
    for (int n = threadIdx.x; n < N_; n += 256) {
        float tx = T[2 * n], ty = T[2 * n + 1];
        bool val = (fabsf(tx) + fabsf(ty)) > 1e-6f;
        if (val) {
            mnx = fminf(mnx, tx); mxx = fmaxf(mxx, tx);
            mny = fminf(mny, ty); mxy = fmaxf(mxy, ty);
        }
    }
    #pragma unroll
    for (int off = 32; off; off >>= 1) {
        mnx = fminf(mnx, __shfl_down(mnx, off));
        mxx = fmaxf(mxx, __shfl_down(mxx, off));
        mny = fminf(mny, __shfl_down(mny, off));
        mxy = fmaxf(mxy, __shfl_down(mxy, off));
    }
    __shared__ float sh[4][4];
    __shared__ float wh[2];
    int wave = threadIdx.x >> 6, lane = threadIdx.x & 63;
    if (lane == 0) { sh[wave][0] = mnx; sh[wave][1] = mxx; sh[wave][2] = mny; sh[wave][3] = mxy; }
    __syncthreads();
    if (threadIdx.x == 0) {
        float a = sh[0][0], bb = sh[0][1], c = sh[0][2], d = sh[0][3];
        for (int w = 1; w < 4; w++) {
            a = fminf(a, sh[w][0]); bb = fmaxf(bb, sh[w][1]);
            c = fminf(c, sh[w][2]); d = fmaxf(d, sh[w][3]);
        }
        // if no valid point: bb-a = -2e30 -> fmaxf gives 224 (matches reference's where)
        wh[0] = fmaxf(224.0f, bb - a + 1e-6f);
        wh[1] = fmaxf(224.0f, d - c + 1e-6f);
    }
    __syncthreads();
    float whx = wh[0], why = wh[1];

    float P00 = P[0], P01 = P[1], P02 = P[2], P03 = P[3];
    float P10 = P[4], P11 = P[5], P12 = P[6], P13 = P[7];
    float P20 = P[8], P21 = P[9], P22 = P[10], P23 = P[11];

    float errsum = 0.f;
    for (int n = threadIdx.x; n < N_; n += 256) {
        float x = Q[3 * n], y = Q[3 * n + 1], z = Q[3 * n + 2];
        float p0 = P00 * x + P01 * y + P02 * z + P03;
        float p1 = P10 * x + P11 * y + P12 * z + P13;
        float p2 = P20 * x + P21 * y + P22 * z + P23;
        float den = p2 + 1e-10f;
        float tx = T[2 * n], ty = T[2 * n + 1];
        float ex = (p0 / den - tx) / whx;
        float ey = (p1 / den - ty) / why;
        errsum += ex * ex + ey * ey;
    }
    #pragma unroll
    for (int off = 32; off; off >>= 1) errsum += __shfl_down(errsum, off);
    __shared__ float se2[4];
    if (lane == 0) se2[wave] = errsum;
    __syncthreads();
    if (threadIdx.x == 0) {
        float s = se2[0] + se2[1] + se2[2] + se2[3];
        atomicAdd(&sums[1], (double)(s / (float)N_));   // view_loss for this (v,b,f)
    }
}

// ---------------- attention BCE loss (the big one: 268 MB read) ----------------
__global__ __launch_bounds__(256) void att_kernel(const float* __restrict__ corr,
                                                  const int* __restrict__ vis,
                                                  double* sums) {
    __shared__ unsigned char vs[B_ * N_];    // frame-0 visibility, 4 KB
    for (int t = threadIdx.x; t < B_ * N_; t += 256) {
        int b = t >> 10, n = t & (N_ - 1);
        vs[t] = (vis[b * (F_ * N_) + n] > 0) ? 1 : 0;
    }
    __syncthreads();

    const float4* c4 = (const float4*)corr;
    const unsigned total4 = (unsigned)(V_ * V_ * B_) * (unsigned)(N_ * (N_ / 4)); // 16,777,216
    const unsigned stride = gridDim.x * blockDim.x;
    float acc = 0.f;
    for (unsigned q = blockIdx.x * blockDim.x + threadIdx.x; q < total4; q += stride) {
        float4 x4 = c4[q];
        unsigned base = q * 4u;
        int j0 = (int)(base & (N_ - 1));
        int i  = (int)((base >> 10) & (N_ - 1));
        int b  = (int)((base >> 20) & 3);
        const unsigned char* vrow = &vs[b << 10];
        float vi = (float)vrow[i];
        #pragma unroll
        for (int k = 0; k < 4; k++) {
            float x = (&x4.x)[k];
            int j = j0 + k;
            int d = abs(i - j);
            float band = (d == 0) ? 1.0f : (d == 1) ? 0.7f : (d == 2) ? 0.49f : 0.0f;
            float pair = (vi != 0.f || vrow[j] != 0) ? 1.0f : 0.0f;
            float gt = band * pair;
            float w = 1.0f + 2.0f * gt;
            float ax = fabsf(x);
            float sp = __logf(1.0f + __expf(-ax));      // log1p(exp(-|x|)), |x|>=0 so arg in (1,2]
            acc += w * (fmaxf(x, 0.0f) - x * gt + sp);
        }
    }
    #pragma unroll
    for (int off = 32; off; off >>= 1) acc += __shfl_down(acc, off);
    __shared__ float sw[4];
    int wave = threadIdx.x >> 6, lane = threadIdx.x & 63;
    if (lane == 0) sw[wave] = acc;
    __syncthreads();
    if (threadIdx.x == 0) {
        float s = sw[0] + sw[1] + sw[2] + sw[3];
        atomicAdd(&sums[2], (double)s);
    }
}

// ---------------- finalize ----------------
__global__ void finalize_kernel(const double* sums, const unsigned* mm, float* out) {
    unsigned cnt = mm[0];
    double num = (double)cnt * 3.0;
    double mse = sums[0] / fmax(num, 1.0);
    float rng = -1e30f;
    for (int c = 0; c < 3; c++) {
        float mnv = ordDecode(mm[1 + c]);
        float mxv = ordDecode(mm[4 + c]);
        rng = fmaxf(rng, mxv - mnv);
    }
    float scale = rng + 1e-6f;
    if (cnt == 0) scale = 1.0f;
    float rec = (float)mse / (scale * scale);
    float ident = (float)(sums[1] / (double)(V_ * B_ * F_));
    float att = (float)(sums[2] / ((double)V_ * V_ * B_ * N_ * N_));
    float total = rec + 1.0f * ident + 0.5f * att;
    out[0] = total; out[1] = rec; out[2] = ident; out[3] = att;
}

extern "C" void kernel_launch(void* const* d_in, const int* in_sizes, int n_in,
                              void* d_out, int out_size, void* d_ws, size_t ws_size,
                              hipStream_t stream) {
    const float* refined = (const float*)d_in[0];   // [B,F,N,3]
    const float* gtp     = (const float*)d_in[1];   // [B,F,N,3]
    const int*   vis     = (const int*)d_in[2];     // [B,F,N]
    const float* proj    = (const float*)d_in[3];   // [V,B,3,4]
    const float* tracks  = (const float*)d_in[4];   // [V,B,F,N,2]
    const float* corr    = (const float*)d_in[5];   // [V,V,B,N,N]
    float* out = (float*)d_out;

    double*   sums = (double*)d_ws;
    unsigned* mm   = (unsigned*)((char*)d_ws + 24);

    init_ws<<<1, 64, 0, stream>>>(sums, mm);
    rec_kernel<<<(B_ * F_ * N_) / 256, 256, 0, stream>>>(refined, gtp, vis, sums, mm);
    ident_kernel<<<V_ * B_ * F_, 256, 0, stream>>>(refined, proj, tracks, sums);
    att_kernel<<<4096, 256, 0, stream>>>(corr, vis, sums);
    finalize_kernel<<<1, 1, 0, stream>>>(sums, mm, out);
}

// Round 2
// 376.206 us; speedup vs baseline: 1.1026x; 1.1026x over previous
//
#include <hip/hip_runtime.h>
#include <math.h>

#define B_ 4
#define F_ 16
#define N_ 1024
#define V_ 4

#define ATT_BLOCKS 4096   // each handles 16 rows x 1024 cols = 16384 floats
#define REC_BLOCKS 256    // each handles 256 points
#define ID_BLOCKS  256    // one per (v,b,f)

// ---------------- workspace layout (all slots written unconditionally every launch) ----
//   double attp[4096];          offset 0       (32768 B)
//   float  recp[256*8];         offset 32768   (8192 B)   {se,c,mn0,mn1,mn2,mx0,mx1,mx2}
//   float  idp[256];            offset 40960   (1024 B)

__device__ __forceinline__ float softplusf(float x) {
    float ax = fabsf(x);
    float e = __expf(-ax);                 // exp(-|x|) in (0,1]
    return fmaxf(x, 0.0f) + __logf(1.0f + e);
}

__global__ __launch_bounds__(256) void mega_kernel(const float* __restrict__ pred,
                                                   const float* __restrict__ gt,
                                                   const int* __restrict__ vis,
                                                   const float* __restrict__ proj,
                                                   const float* __restrict__ tracks,
                                                   const float* __restrict__ corr,
                                                   double* __restrict__ attp,
                                                   float* __restrict__ recp,
                                                   float* __restrict__ idp) {
    const int blk = blockIdx.x;
    const int t = threadIdx.x;
    const int wave = t >> 6, lane = t & 63;

    if (blk < ATT_BLOCKS) {
        // ---------------- attention BCE slab: rows [row0, row0+16) of matrix (vv,b) ----
        const int b = (blk >> 6) & 3;
        const int row0 = (blk & 63) << 4;
        __shared__ unsigned char vs[N_];     // frame-0 visibility for this b
        {
            int4 v4 = ((const int4*)(vis + b * (F_ * N_)))[t];
            vs[4 * t + 0] = v4.x > 0;
            vs[4 * t + 1] = v4.y > 0;
            vs[4 * t + 2] = v4.z > 0;
            vs[4 * t + 3] = v4.w > 0;
        }
        __syncthreads();

        const float4* base4 = (const float4*)corr + (size_t)blk * 4096;
        const int j0 = 4 * t;                // this thread's column group (fixed)
        float acc = 0.f;
        float4 cur = base4[t];
        #pragma unroll
        for (int k = 0; k < 16; k++) {
            float4 nxt = cur;
            if (k < 15) nxt = base4[(k + 1) * 256 + t];
            const int i = row0 + k;
            float x0 = cur.x, x1 = cur.y, x2 = cur.z, x3 = cur.w;
            float sp0 = softplusf(x0), sp1 = softplusf(x1);
            float sp2 = softplusf(x2), sp3 = softplusf(x3);
            acc += (sp0 + sp1) + (sp2 + sp3);
            if (j0 >= i - 5 && j0 <= i + 2) {       // chunk intersects |i-j|<=2 band
                float xs[4] = {x0, x1, x2, x3};
                float sps[4] = {sp0, sp1, sp2, sp3};
                unsigned char vi = vs[i];
                #pragma unroll
                for (int kk = 0; kk < 4; kk++) {
                    int j = j0 + kk;
                    int d = (i > j) ? (i - j) : (j - i);
                    if (d <= 2) {
                        if (vi | vs[j]) {
                            float g = (d == 0) ? 1.0f : ((d == 1) ? 0.7f : 0.49f);
                            // full bce = (1+2g)*(sp - x*g); we already added sp
                            acc += 2.f * g * sps[kk] - (1.f + 2.f * g) * xs[kk] * g;
                        }
                    }
                }
            }
            cur = nxt;
        }
        #pragma unroll
        for (int off = 32; off; off >>= 1) acc += __shfl_down(acc, off);
        __shared__ double sw[4];
        if (lane == 0) sw[wave] = (double)acc;
        __syncthreads();
        if (t == 0) attp[blk] = (sw[0] + sw[1]) + (sw[2] + sw[3]);

    } else if (blk < ATT_BLOCKS + REC_BLOCKS) {
        // ---------------- reconstruction partials: 256 points ----------------
        const int r = blk - ATT_BLOCKS;
        const int p = r * 256 + t;
        bool m = vis[p] > 0;
        float gx = gt[3 * p], gy = gt[3 * p + 1], gz = gt[3 * p + 2];
        float px = pred[3 * p], py = pred[3 * p + 1], pz = pred[3 * p + 2];
        float se = 0.f;
        if (m) {
            float dx = px - gx, dy = py - gy, dz = pz - gz;
            se = dx * dx + dy * dy + dz * dz;
        }
        float mn0 = m ? gx : 1e30f, mn1 = m ? gy : 1e30f, mn2 = m ? gz : 1e30f;
        float mx0 = m ? gx : -1e30f, mx1 = m ? gy : -1e30f, mx2 = m ? gz : -1e30f;
        float c = m ? 1.f : 0.f;
        #pragma unroll
        for (int off = 32; off; off >>= 1) {
            se += __shfl_down(se, off);
            c  += __shfl_down(c, off);
            mn0 = fminf(mn0, __shfl_down(mn0, off));
            mn1 = fminf(mn1, __shfl_down(mn1, off));
            mn2 = fminf(mn2, __shfl_down(mn2, off));
            mx0 = fmaxf(mx0, __shfl_down(mx0, off));
            mx1 = fmaxf(mx1, __shfl_down(mx1, off));
            mx2 = fmaxf(mx2, __shfl_down(mx2, off));
        }
        __shared__ float sh[4][8];
        if (lane == 0) {
            sh[wave][0] = se; sh[wave][1] = c;
            sh[wave][2] = mn0; sh[wave][3] = mn1; sh[wave][4] = mn2;
            sh[wave][5] = mx0; sh[wave][6] = mx1; sh[wave][7] = mx2;
        }
        __syncthreads();
        if (t == 0) {
            se = sh[0][0]; c = sh[0][1];
            mn0 = sh[0][2]; mn1 = sh[0][3]; mn2 = sh[0][4];
            mx0 = sh[0][5]; mx1 = sh[0][6]; mx2 = sh[0][7];
            for (int w = 1; w < 4; w++) {
                se += sh[w][0]; c += sh[w][1];
                mn0 = fminf(mn0, sh[w][2]); mn1 = fminf(mn1, sh[w][3]); mn2 = fminf(mn2, sh[w][4]);
                mx0 = fmaxf(mx0, sh[w][5]); mx1 = fmaxf(mx1, sh[w][6]); mx2 = fmaxf(mx2, sh[w][7]);
            }
            float* o = recp + r * 8;
            o[0] = se; o[1] = c;
            o[2] = mn0; o[3] = mn1; o[4] = mn2;
            o[5] = mx0; o[6] = mx1; o[7] = mx2;
        }

    } else {
        // ---------------- identity (reprojection) per (v,b,f) ----------------
        const int idx = blk - (ATT_BLOCKS + REC_BLOCKS);
        const int v = idx / (B_ * F_);
        const int b = (idx / F_) % B_;
        const int f = idx % F_;
        const float* P = proj + ((size_t)(v * B_ + b)) * 12;
        const float* T = tracks + ((size_t)((v * B_ + b) * F_ + f)) * N_ * 2;
        const float* Q = pred + ((size_t)(b * F_ + f)) * N_ * 3;

        float mnx = 1e30f, mny = 1e30f, mxx = -1e30f, mxy = -1e30f;
        for (int n = t; n < N_; n += 256) {
            float tx = T[2 * n], ty = T[2 * n + 1];
            if ((fabsf(tx) + fabsf(ty)) > 1e-6f) {
                mnx = fminf(mnx, tx); mxx = fmaxf(mxx, tx);
                mny = fminf(mny, ty); mxy = fmaxf(mxy, ty);
            }
        }
        #pragma unroll
        for (int off = 32; off; off >>= 1) {
            mnx = fminf(mnx, __shfl_down(mnx, off));
            mxx = fmaxf(mxx, __shfl_down(mxx, off));
            mny = fminf(mny, __shfl_down(mny, off));
            mxy = fmaxf(mxy, __shfl_down(mxy, off));
        }
        __shared__ float shi[4][4];
        __shared__ float wh[2];
        if (lane == 0) { shi[wave][0] = mnx; shi[wave][1] = mxx; shi[wave][2] = mny; shi[wave][3] = mxy; }
        __syncthreads();
        if (t == 0) {
            float a = shi[0][0], bb = shi[0][1], c = shi[0][2], d = shi[0][3];
            for (int w = 1; w < 4; w++) {
                a = fminf(a, shi[w][0]); bb = fmaxf(bb, shi[w][1]);
                c = fminf(c, shi[w][2]); d = fmaxf(d, shi[w][3]);
            }
            wh[0] = fmaxf(224.0f, bb - a + 1e-6f);   // no-valid case: -2e30 -> 224
            wh[1] = fmaxf(224.0f, d - c + 1e-6f);
        }
        __syncthreads();
        float whx = wh[0], why = wh[1];

        float P00 = P[0], P01 = P[1], P02 = P[2], P03 = P[3];
        float P10 = P[4], P11 = P[5], P12 = P[6], P13 = P[7];
        float P20 = P[8], P21 = P[9], P22 = P[10], P23 = P[11];

        float errsum = 0.f;
        for (int n = t; n < N_; n += 256) {
            float x = Q[3 * n], y = Q[3 * n + 1], z = Q[3 * n + 2];
            float p0 = P00 * x + P01 * y + P02 * z + P03;
            float p1 = P10 * x + P11 * y + P12 * z + P13;
            float p2 = P20 * x + P21 * y + P22 * z + P23;
            float den = p2 + 1e-10f;
            float tx = T[2 * n], ty = T[2 * n + 1];
            float ex = (p0 / den - tx) / whx;
            float ey = (p1 / den - ty) / why;
            errsum += ex * ex + ey * ey;
        }
        #pragma unroll
        for (int off = 32; off; off >>= 1) errsum += __shfl_down(errsum, off);
        __shared__ float se2[4];
        if (lane == 0) se2[wave] = errsum;
        __syncthreads();
        if (t == 0) idp[idx] = (se2[0] + se2[1] + se2[2] + se2[3]) / (float)N_;
    }
}

__global__ __launch_bounds__(256) void fin_kernel(const double* __restrict__ attp,
                                                  const float* __restrict__ recp,
                                                  const float* __restrict__ idp,
                                                  float* __restrict__ out) {
    const int t = threadIdx.x;
    const int wave = t >> 6, lane = t & 63;

    double a = 0.0;
    for (int k = t; k < ATT_BLOCKS; k += 256) a += attp[k];
    const float* rp = recp + t * 8;
    double se = (double)rp[0];
    double c  = (double)rp[1];
    float mn0 = rp[2], mn1 = rp[3], mn2 = rp[4];
    float mx0 = rp[5], mx1 = rp[6], mx2 = rp[7];
    double id = (double)idp[t];

    #pragma unroll
    for (int off = 32; off; off >>= 1) {
        a  += __shfl_down(a, off);
        se += __shfl_down(se, off);
        c  += __shfl_down(c, off);
        id += __shfl_down(id, off);
        mn0 = fminf(mn0, __shfl_down(mn0, off));
        mn1 = fminf(mn1, __shfl_down(mn1, off));
        mn2 = fminf(mn2, __shfl_down(mn2, off));
        mx0 = fmaxf(mx0, __shfl_down(mx0, off));
        mx1 = fmaxf(mx1, __shfl_down(mx1, off));
        mx2 = fmaxf(mx2, __shfl_down(mx2, off));
    }
    __shared__ double sa[4], sse[4], sc[4], sid[4];
    __shared__ float smn[3][4], smx[3][4];
    if (lane == 0) {
        sa[wave] = a; sse[wave] = se; sc[wave] = c; sid[wave] = id;
        smn[0][wave] = mn0; smn[1][wave] = mn1; smn[2][wave] = mn2;
        smx[0][wave] = mx0; smx[1][wave] = mx1; smx[2][wave] = mx2;
    }
    __syncthreads();
    if (t == 0) {
        a = sa[0]; se = sse[0]; c = sc[0]; id = sid[0];
        mn0 = smn[0][0]; mn1 = smn[1][0]; mn2 = smn[2][0];
        mx0 = smx[0][0]; mx1 = smx[1][0]; mx2 = smx[2][0];
        for (int w = 1; w < 4; w++) {
            a += sa[w]; se += sse[w]; c += sc[w]; id += sid[w];
            mn0 = fminf(mn0, smn[0][w]); mn1 = fminf(mn1, smn[1][w]); mn2 = fminf(mn2, smn[2][w]);
            mx0 = fmaxf(mx0, smx[0][w]); mx1 = fmaxf(mx1, smx[1][w]); mx2 = fmaxf(mx2, smx[2][w]);
        }
        double num = c * 3.0;
        double mse = se / fmax(num, 1.0);
        float rng = fmaxf(mx0 - mn0, fmaxf(mx1 - mn1, mx2 - mn2));
        float scale = rng + 1e-6f;
        if (c < 0.5) scale = 1.0f;
        float rec = (float)mse / (scale * scale);
        float ident = (float)(id / (double)(V_ * B_ * F_));
        float att = (float)(a / ((double)V_ * V_ * B_ * N_ * N_));
        float total = rec + 1.0f * ident + 0.5f * att;
        out[0] = total; out[1] = rec; out[2] = ident; out[3] = att;
    }
}

extern "C" void kernel_launch(void* const* d_in, const int* in_sizes, int n_in,
                              void* d_out, int out_size, void* d_ws, size_t ws_size,
                              hipStream_t stream) {
    const float* refined = (const float*)d_in[0];   // [B,F,N,3]
    const float* gtp     = (const float*)d_in[1];   // [B,F,N,3]
    const int*   vis     = (const int*)d_in[2];     // [B,F,N]
    const float* proj    = (const float*)d_in[3];   // [V,B,3,4]
    const float* tracks  = (const float*)d_in[4];   // [V,B,F,N,2]
    const float* corr    = (const float*)d_in[5];   // [V,V,B,N,N]
    float* out = (float*)d_out;

    double* attp = (double*)d_ws;
    float*  recp = (float*)((char*)d_ws + 32768);
    float*  idp  = (float*)((char*)d_ws + 40960);

    mega_kernel<<<ATT_BLOCKS + REC_BLOCKS + ID_BLOCKS, 256, 0, stream>>>(
        refined, gtp, vis, proj, tracks, corr, attp, recp, idp);
    fin_kernel<<<1, 256, 0, stream>>>(attp, recp, idp, out);
}

// Round 4
// 352.913 us; speedup vs baseline: 1.1754x; 1.0660x over previous
//
#include <hip/hip_runtime.h>
#include <math.h>

#define B_ 4
#define F_ 16
#define N_ 1024
#define V_ 4

#define ATT_BLOCKS 4096   // each handles 16 rows x 1024 cols = 16384 floats (64 KB slab)
#define REC_BLOCKS 256    // each handles 256 points
#define ID_BLOCKS  256    // one per (v,b,f)

typedef float vf4 __attribute__((ext_vector_type(4)));   // clang-native float4

// ---------------- workspace layout (all slots written unconditionally every launch) ----
//   double attp[4096];          offset 0       (32768 B)
//   float  recp[256*8];         offset 32768   (8192 B)   {se,c,mn0,mn1,mn2,mx0,mx1,mx2}
//   float  idp[256];            offset 40960   (1024 B)

__device__ __forceinline__ float softplusf(float x) {
    float ax = fabsf(x);
    float e = __expf(-ax);                 // exp(-|x|) in (0,1]
    return fmaxf(x, 0.0f) + __logf(1.0f + e);
}

__global__ __launch_bounds__(256) void mega_kernel(const float* __restrict__ pred,
                                                   const float* __restrict__ gt,
                                                   const int* __restrict__ vis,
                                                   const float* __restrict__ proj,
                                                   const float* __restrict__ tracks,
                                                   const float* __restrict__ corr,
                                                   double* __restrict__ attp,
                                                   float* __restrict__ recp,
                                                   float* __restrict__ idp) {
    const int blk = blockIdx.x;
    const int t = threadIdx.x;
    const int wave = t >> 6, lane = t & 63;

    if (blk < ATT_BLOCKS) {
        // ---------------- attention BCE slab: rows [row0, row0+16) of matrix (vv,b) ----
        const int b = (blk >> 6) & 3;
        const int row0 = (blk & 63) << 4;
        __shared__ unsigned char vs[N_];     // frame-0 visibility for this b
        {
            int4 v4 = ((const int4*)(vis + b * (F_ * N_)))[t];
            vs[4 * t + 0] = v4.x > 0;
            vs[4 * t + 1] = v4.y > 0;
            vs[4 * t + 2] = v4.z > 0;
            vs[4 * t + 3] = v4.w > 0;
        }

        // issue all 16 slab loads up-front: 16 independent nontemporal dwordx4 in flight
        const vf4* base4 = (const vf4*)corr + (size_t)blk * 4096;
        vf4 d[16];
        #pragma unroll
        for (int k = 0; k < 16; k++)
            d[k] = __builtin_nontemporal_load(base4 + k * 256 + t);

        __syncthreads();

        const int j0 = 4 * t;                // this thread's column group (fixed across rows)
        float acc = 0.f;
        #pragma unroll
        for (int k = 0; k < 16; k++) {
            const int i = row0 + k;
            float x0 = d[k].x, x1 = d[k].y, x2 = d[k].z, x3 = d[k].w;
            float sp0 = softplusf(x0), sp1 = softplusf(x1);
            float sp2 = softplusf(x2), sp3 = softplusf(x3);
            acc += (sp0 + sp1) + (sp2 + sp3);
            if (j0 >= i - 5 && j0 <= i + 2) {       // chunk intersects |i-j|<=2 band
                float xs[4] = {x0, x1, x2, x3};
                float sps[4] = {sp0, sp1, sp2, sp3};
                unsigned char vi = vs[i];
                #pragma unroll
                for (int kk = 0; kk < 4; kk++) {
                    int j = j0 + kk;
                    int dd = (i > j) ? (i - j) : (j - i);
                    if (dd <= 2) {
                        if (vi | vs[j]) {
                            float g = (dd == 0) ? 1.0f : ((dd == 1) ? 0.7f : 0.49f);
                            // full bce = (1+2g)*(sp - x*g); sp already added above
                            acc += 2.f * g * sps[kk] - (1.f + 2.f * g) * xs[kk] * g;
                        }
                    }
                }
            }
        }
        #pragma unroll
        for (int off = 32; off; off >>= 1) acc += __shfl_down(acc, off);
        __shared__ double sw[4];
        if (lane == 0) sw[wave] = (double)acc;
        __syncthreads();
        if (t == 0) attp[blk] = (sw[0] + sw[1]) + (sw[2] + sw[3]);

    } else if (blk < ATT_BLOCKS + REC_BLOCKS) {
        // ---------------- reconstruction partials: 256 points ----------------
        const int r = blk - ATT_BLOCKS;
        const int p = r * 256 + t;
        bool m = vis[p] > 0;
        float gx = gt[3 * p], gy = gt[3 * p + 1], gz = gt[3 * p + 2];
        float px = pred[3 * p], py = pred[3 * p + 1], pz = pred[3 * p + 2];
        float se = 0.f;
        if (m) {
            float dx = px - gx, dy = py - gy, dz = pz - gz;
            se = dx * dx + dy * dy + dz * dz;
        }
        float mn0 = m ? gx : 1e30f, mn1 = m ? gy : 1e30f, mn2 = m ? gz : 1e30f;
        float mx0 = m ? gx : -1e30f, mx1 = m ? gy : -1e30f, mx2 = m ? gz : -1e30f;
        float c = m ? 1.f : 0.f;
        #pragma unroll
        for (int off = 32; off; off >>= 1) {
            se += __shfl_down(se, off);
            c  += __shfl_down(c, off);
            mn0 = fminf(mn0, __shfl_down(mn0, off));
            mn1 = fminf(mn1, __shfl_down(mn1, off));
            mn2 = fminf(mn2, __shfl_down(mn2, off));
            mx0 = fmaxf(mx0, __shfl_down(mx0, off));
            mx1 = fmaxf(mx1, __shfl_down(mx1, off));
            mx2 = fmaxf(mx2, __shfl_down(mx2, off));
        }
        __shared__ float sh[4][8];
        if (lane == 0) {
            sh[wave][0] = se; sh[wave][1] = c;
            sh[wave][2] = mn0; sh[wave][3] = mn1; sh[wave][4] = mn2;
            sh[wave][5] = mx0; sh[wave][6] = mx1; sh[wave][7] = mx2;
        }
        __syncthreads();
        if (t == 0) {
            se = sh[0][0]; c = sh[0][1];
            mn0 = sh[0][2]; mn1 = sh[0][3]; mn2 = sh[0][4];
            mx0 = sh[0][5]; mx1 = sh[0][6]; mx2 = sh[0][7];
            for (int w = 1; w < 4; w++) {
                se += sh[w][0]; c += sh[w][1];
                mn0 = fminf(mn0, sh[w][2]); mn1 = fminf(mn1, sh[w][3]); mn2 = fminf(mn2, sh[w][4]);
                mx0 = fmaxf(mx0, sh[w][5]); mx1 = fmaxf(mx1, sh[w][6]); mx2 = fmaxf(mx2, sh[w][7]);
            }
            float* o = recp + r * 8;
            o[0] = se; o[1] = c;
            o[2] = mn0; o[3] = mn1; o[4] = mn2;
            o[5] = mx0; o[6] = mx1; o[7] = mx2;
        }

    } else {
        // ---------------- identity (reprojection) per (v,b,f) ----------------
        const int idx = blk - (ATT_BLOCKS + REC_BLOCKS);
        const int v = idx / (B_ * F_);
        const int b = (idx / F_) % B_;
        const int f = idx % F_;
        const float* P = proj + ((size_t)(v * B_ + b)) * 12;
        const float* T = tracks + ((size_t)((v * B_ + b) * F_ + f)) * N_ * 2;
        const float* Q = pred + ((size_t)(b * F_ + f)) * N_ * 3;

        float mnx = 1e30f, mny = 1e30f, mxx = -1e30f, mxy = -1e30f;
        for (int n = t; n < N_; n += 256) {
            float tx = T[2 * n], ty = T[2 * n + 1];
            if ((fabsf(tx) + fabsf(ty)) > 1e-6f) {
                mnx = fminf(mnx, tx); mxx = fmaxf(mxx, tx);
                mny = fminf(mny, ty); mxy = fmaxf(mxy, ty);
            }
        }
        #pragma unroll
        for (int off = 32; off; off >>= 1) {
            mnx = fminf(mnx, __shfl_down(mnx, off));
            mxx = fmaxf(mxx, __shfl_down(mxx, off));
            mny = fminf(mny, __shfl_down(mny, off));
            mxy = fmaxf(mxy, __shfl_down(mxy, off));
        }
        __shared__ float shi[4][4];
        __shared__ float wh[2];
        if (lane == 0) { shi[wave][0] = mnx; shi[wave][1] = mxx; shi[wave][2] = mny; shi[wave][3] = mxy; }
        __syncthreads();
        if (t == 0) {
            float a = shi[0][0], bb = shi[0][1], c = shi[0][2], d = shi[0][3];
            for (int w = 1; w < 4; w++) {
                a = fminf(a, shi[w][0]); bb = fmaxf(bb, shi[w][1]);
                c = fminf(c, shi[w][2]); d = fmaxf(d, shi[w][3]);
            }
            wh[0] = fmaxf(224.0f, bb - a + 1e-6f);   // no-valid case: -2e30 -> 224
            wh[1] = fmaxf(224.0f, d - c + 1e-6f);
        }
        __syncthreads();
        float whx = wh[0], why = wh[1];

        float P00 = P[0], P01 = P[1], P02 = P[2], P03 = P[3];
        float P10 = P[4], P11 = P[5], P12 = P[6], P13 = P[7];
        float P20 = P[8], P21 = P[9], P22 = P[10], P23 = P[11];

        float errsum = 0.f;
        for (int n = t; n < N_; n += 256) {
            float x = Q[3 * n], y = Q[3 * n + 1], z = Q[3 * n + 2];
            float p0 = P00 * x + P01 * y + P02 * z + P03;
            float p1 = P10 * x + P11 * y + P12 * z + P13;
            float p2 = P20 * x + P21 * y + P22 * z + P23;
            float den = p2 + 1e-10f;
            float tx = T[2 * n], ty = T[2 * n + 1];
            float ex = (p0 / den - tx) / whx;
            float ey = (p1 / den - ty) / why;
            errsum += ex * ex + ey * ey;
        }
        #pragma unroll
        for (int off = 32; off; off >>= 1) errsum += __shfl_down(errsum, off);
        __shared__ float se2[4];
        if (lane == 0) se2[wave] = errsum;
        __syncthreads();
        if (t == 0) idp[idx] = (se2[0] + se2[1] + se2[2] + se2[3]) / (float)N_;
    }
}

__global__ __launch_bounds__(256) void fin_kernel(const double* __restrict__ attp,
                                                  const float* __restrict__ recp,
                                                  const float* __restrict__ idp,
                                                  float* __restrict__ out) {
    const int t = threadIdx.x;
    const int wave = t >> 6, lane = t & 63;

    double a = 0.0;
    #pragma unroll
    for (int k = 0; k < ATT_BLOCKS / 256; k++) a += attp[k * 256 + t];
    const float* rp = recp + t * 8;
    double se = (double)rp[0];
    double c  = (double)rp[1];
    float mn0 = rp[2], mn1 = rp[3], mn2 = rp[4];
    float mx0 = rp[5], mx1 = rp[6], mx2 = rp[7];
    double id = (double)idp[t];

    #pragma unroll
    for (int off = 32; off; off >>= 1) {
        a  += __shfl_down(a, off);
        se += __shfl_down(se, off);
        c  += __shfl_down(c, off);
        id += __shfl_down(id, off);
        mn0 = fminf(mn0, __shfl_down(mn0, off));
        mn1 = fminf(mn1, __shfl_down(mn1, off));
        mn2 = fminf(mn2, __shfl_down(mn2, off));
        mx0 = fmaxf(mx0, __shfl_down(mx0, off));
        mx1 = fmaxf(mx1, __shfl_down(mx1, off));
        mx2 = fmaxf(mx2, __shfl_down(mx2, off));
    }
    __shared__ double sa[4], sse[4], sc[4], sid[4];
    __shared__ float smn[3][4], smx[3][4];
    if (lane == 0) {
        sa[wave] = a; sse[wave] = se; sc[wave] = c; sid[wave] = id;
        smn[0][wave] = mn0; smn[1][wave] = mn1; smn[2][wave] = mn2;
        smx[0][wave] = mx0; smx[1][wave] = mx1; smx[2][wave] = mx2;
    }
    __syncthreads();
    if (t == 0) {
        a = sa[0]; se = sse[0]; c = sc[0]; id = sid[0];
        mn0 = smn[0][0]; mn1 = smn[1][0]; mn2 = smn[2][0];
        mx0 = smx[0][0]; mx1 = smx[1][0]; mx2 = smx[2][0];
        for (int w = 1; w < 4; w++) {
            a += sa[w]; se += sse[w]; c += sc[w]; id += sid[w];
            mn0 = fminf(mn0, smn[0][w]); mn1 = fminf(mn1, smn[1][w]); mn2 = fminf(mn2, smn[2][w]);
            mx0 = fmaxf(mx0, smx[0][w]); mx1 = fmaxf(mx1, smx[1][w]); mx2 = fmaxf(mx2, smx[2][w]);
        }
        double num = c * 3.0;
        double mse = se / fmax(num, 1.0);
        float rng = fmaxf(mx0 - mn0, fmaxf(mx1 - mn1, mx2 - mn2));
        float scale = rng + 1e-6f;
        if (c < 0.5) scale = 1.0f;
        float rec = (float)mse / (scale * scale);
        float ident = (float)(id / (double)(V_ * B_ * F_));
        float att = (float)(a / ((double)V_ * V_ * B_ * N_ * N_));
        float total = rec + 1.0f * ident + 0.5f * att;
        out[0] = total; out[1] = rec; out[2] = ident; out[3] = att;
    }
}

extern "C" void kernel_launch(void* const* d_in, const int* in_sizes, int n_in,
                              void* d_out, int out_size, void* d_ws, size_t ws_size,
                              hipStream_t stream) {
    const float* refined = (const float*)d_in[0];   // [B,F,N,3]
    const float* gtp     = (const float*)d_in[1];   // [B,F,N,3]
    const int*   vis     = (const int*)d_in[2];     // [B,F,N]
    const float* proj    = (const float*)d_in[3];   // [V,B,3,4]
    const float* tracks  = (const float*)d_in[4];   // [V,B,F,N,2]
    const float* corr    = (const float*)d_in[5];   // [V,V,B,N,N]
    float* out = (float*)d_out;

    double* attp = (double*)d_ws;
    float*  recp = (float*)((char*)d_ws + 32768);
    float*  idp  = (float*)((char*)d_ws + 40960);

    mega_kernel<<<ATT_BLOCKS + REC_BLOCKS + ID_BLOCKS, 256, 0, stream>>>(
        refined, gtp, vis, proj, tracks, corr, attp, recp, idp);
    fin_kernel<<<1, 256, 0, stream>>>(attp, recp, idp, out);
}